// Round 1
// baseline (203.188 us; speedup 1.0000x reference)
//
#include <hip/hip_runtime.h>

typedef __attribute__((ext_vector_type(8))) short short8;
typedef __attribute__((ext_vector_type(4))) float f32x4;

#define DM 1024
#define SL 2048
#define NH 16
#define DKH 64
#define NB 2

__device__ __forceinline__ unsigned short f2bf(float f) {
    union { float f; unsigned int u; } a; a.f = f;
    unsigned int r = a.u + 0x7FFFu + ((a.u >> 16) & 1u);
    return (unsigned short)(r >> 16);
}

__device__ __forceinline__ void gl_lds16(const void* g, void* l) {
    __builtin_amdgcn_global_load_lds(
        (__attribute__((address_space(1))) void*)(g),
        (__attribute__((address_space(3))) void*)(l), 16, 0, 0);
}

// ---------------- fp32 -> bf16 conversion (x + 4 weights; wq scaled by 0.125) ----
__global__ __launch_bounds__(256) void convert_kernel(
    const float* __restrict__ x,  const float* __restrict__ wq,
    const float* __restrict__ wk, const float* __restrict__ wv,
    const float* __restrict__ wo,
    unsigned short* __restrict__ xb,  unsigned short* __restrict__ wqb,
    unsigned short* __restrict__ wkb, unsigned short* __restrict__ wvb,
    unsigned short* __restrict__ wob)
{
    const int NX = NB * SL * DM;       // 4M
    const int NW = DM * DM;            // 1M
    int t4 = (blockIdx.x * 256 + threadIdx.x) * 4;
    const float* src; unsigned short* dst; int off; float scale = 1.0f;
    if (t4 < NX)              { src = x;  dst = xb;  off = t4; }
    else if (t4 < NX + NW)    { src = wq; dst = wqb; off = t4 - NX; scale = 0.125f; }
    else if (t4 < NX + 2*NW)  { src = wk; dst = wkb; off = t4 - NX - NW; }
    else if (t4 < NX + 3*NW)  { src = wv; dst = wvb; off = t4 - NX - 2*NW; }
    else                      { src = wo; dst = wob; off = t4 - NX - 3*NW; }
    float4 v = *(const float4*)(src + off);
    unsigned long long p =
        (unsigned long long)f2bf(v.x * scale)
      | ((unsigned long long)f2bf(v.y * scale) << 16)
      | ((unsigned long long)f2bf(v.z * scale) << 32)
      | ((unsigned long long)f2bf(v.w * scale) << 48);
    *(unsigned long long*)(dst + off) = p;
}

// ---------------- GEMM  C[m][n] = sum_k A[m][k] * Bw[n][k]  (both K-major) ------
// MODE 0: write bf16 Q/K/V in [B,H,S,64] layout (Bw = [3072][1024] fused weights)
// MODE 1: write fp32 row-major [4096][1024] to `of`
template<int MODE>
__global__ __launch_bounds__(256) void gemm_bt(
    const unsigned short* __restrict__ A,
    const unsigned short* __restrict__ Bw,
    unsigned short* __restrict__ oq, unsigned short* __restrict__ ok,
    unsigned short* __restrict__ ov, float* __restrict__ of)
{
    __shared__ __align__(16) unsigned short As[128 * 32];
    __shared__ __align__(16) unsigned short Bs[128 * 32];
    const int tid  = threadIdx.x;
    const int lane = tid & 63;
    const int wave = tid >> 6;
    const int wm = (wave >> 1) * 64, wn = (wave & 1) * 64;
    const int bx = blockIdx.x, by = blockIdx.y;
    const int c  = lane & 15;
    const int kg = (lane >> 4) * 8;      // k sub-group (elems)

    f32x4 acc[4][4];
    #pragma unroll
    for (int i = 0; i < 4; i++)
        #pragma unroll
        for (int j = 0; j < 4; j++) acc[i][j] = (f32x4){0.f, 0.f, 0.f, 0.f};

    const char* Ab = (const char*)A  + by * 128 * (DM * 2);
    const char* Bb = (const char*)Bw + bx * 128 * (DM * 2);

    for (int k0 = 0; k0 < DM; k0 += 32) {
        #pragma unroll
        for (int i = 0; i < 2; i++) {
            int lin  = i * 4096 + tid * 16;   // bytes within 8KB tile
            int row  = lin >> 6;              // 64B per BK-row
            int colb = lin & 63;
            gl_lds16(Ab + row * (DM * 2) + k0 * 2 + colb, (char*)As + lin);
            gl_lds16(Bb + row * (DM * 2) + k0 * 2 + colb, (char*)Bs + lin);
        }
        __syncthreads();
        short8 a[4], bfr[4];
        #pragma unroll
        for (int mi = 0; mi < 4; mi++)
            a[mi] = *(const short8*)&As[(wm + mi * 16 + c) * 32 + kg];
        #pragma unroll
        for (int ni = 0; ni < 4; ni++)
            bfr[ni] = *(const short8*)&Bs[(wn + ni * 16 + c) * 32 + kg];
        #pragma unroll
        for (int mi = 0; mi < 4; mi++)
            #pragma unroll
            for (int ni = 0; ni < 4; ni++)
                acc[mi][ni] = __builtin_amdgcn_mfma_f32_16x16x32_bf16(
                    a[mi], bfr[ni], acc[mi][ni], 0, 0, 0);
        __syncthreads();
    }

    const int r4 = (lane >> 4) * 4;
    if (MODE == 0) {
        const int mat = (bx * 128) >> 10;                 // 0=q,1=k,2=v
        unsigned short* outb = (mat == 0) ? oq : (mat == 1) ? ok : ov;
        const int nb = bx * 128 - (mat << 10);
        #pragma unroll
        for (int mi = 0; mi < 4; mi++) {
            int m_g = by * 128 + wm + mi * 16 + r4;
            int b_  = m_g >> 11, s_ = m_g & 2047;
            #pragma unroll
            for (int ni = 0; ni < 4; ni++) {
                int n_l = nb + wn + ni * 16 + c;
                int h = n_l >> 6, dk = n_l & 63;
                #pragma unroll
                for (int j = 0; j < 4; j++)
                    outb[((b_ * NH + h) * SL + (s_ + j)) * DKH + dk] = f2bf(acc[mi][ni][j]);
            }
        }
    } else {
        #pragma unroll
        for (int mi = 0; mi < 4; mi++) {
            int m_g = by * 128 + wm + mi * 16 + r4;
            #pragma unroll
            for (int ni = 0; ni < 4; ni++) {
                int n_g = bx * 128 + wn + ni * 16 + c;
                #pragma unroll
                for (int j = 0; j < 4; j++)
                    of[(m_g + j) * DM + n_g] = acc[mi][ni][j];
            }
        }
    }
}

// ---------------- causal flash attention --------------------------------------
// grid (S/128, H, B), block 256 (4 waves x 32 q-rows). KV tiles of 64.
__global__ __launch_bounds__(256) void attn_kernel(
    const unsigned short* __restrict__ Q,   // [B*H][S][64] bf16 (scores pre-scaled)
    const unsigned short* __restrict__ K,
    const unsigned short* __restrict__ V,
    unsigned short* __restrict__ O)         // [B*S][1024] bf16 head-concat
{
    __shared__ __align__(16) unsigned short Kl[64 * 72];       // [kv][dk], pad 8
    __shared__ __align__(16) unsigned short Vt[64 * 72];       // [dk][kv], pad 8
    __shared__ __align__(16) unsigned short Pl[4 * 32 * 72];   // per-wave [q][kv]
    const int tid = threadIdx.x, lane = tid & 63, wave = tid >> 6;
    const int h = blockIdx.y, b = blockIdx.z;
    const int bh = b * NH + h;
    const int qb_blk = blockIdx.x * 128;
    const int qw = qb_blk + wave * 32;
    const unsigned short* Qg = Q + bh * (SL * DKH);
    const unsigned short* Kg = K + bh * (SL * DKH);
    const unsigned short* Vg = V + bh * (SL * DKH);
    const int c  = lane & 15;
    const int kg = (lane >> 4) * 8;
    const int r4 = (lane >> 4) * 4;

    // Q fragments in registers (A-layout)
    short8 aq[2][2];
    #pragma unroll
    for (int mt = 0; mt < 2; mt++)
        #pragma unroll
        for (int kt = 0; kt < 2; kt++)
            aq[mt][kt] = *(const short8*)&Qg[(qw + mt * 16 + c) * DKH + kt * 32 + kg];

    f32x4 acc[2][4];
    #pragma unroll
    for (int i = 0; i < 2; i++)
        #pragma unroll
        for (int j = 0; j < 4; j++) acc[i][j] = (f32x4){0.f, 0.f, 0.f, 0.f};
    float mrun[2][4], lrun[2][4];
    #pragma unroll
    for (int i = 0; i < 2; i++)
        #pragma unroll
        for (int j = 0; j < 4; j++) { mrun[i][j] = -1e30f; lrun[i][j] = 0.f; }

    const int nkv = qb_blk + 128;   // causal: kv < qtile_end
    for (int kv0 = 0; kv0 < nkv; kv0 += 64) {
        __syncthreads();   // protect prior-iter LDS reads from overwrite
        {   // stage K tile: coalesced 32B/thread
            int r = tid >> 2, cb = (tid & 3) << 4;
            const unsigned short* src = Kg + (kv0 + r) * DKH + cb;
            short8 v0 = *(const short8*)(src);
            short8 v1 = *(const short8*)(src + 8);
            *(short8*)&Kl[r * 72 + cb]     = v0;
            *(short8*)&Kl[r * 72 + cb + 8] = v1;
        }
        {   // stage V transposed: bf16x2 coalesced loads, b128 writes
            int d0 = (tid & 31) * 2, kc = (tid >> 5) * 8;
            short8 sa, sb;
            #pragma unroll
            for (int i = 0; i < 8; i++) {
                unsigned int pr = *(const unsigned int*)&Vg[(kv0 + kc + i) * DKH + d0];
                sa[i] = (short)(pr & 0xFFFFu);
                sb[i] = (short)(pr >> 16);
            }
            *(short8*)&Vt[d0 * 72 + kc]       = sa;
            *(short8*)&Vt[(d0 + 1) * 72 + kc] = sb;
        }
        __syncthreads();

        // S = Q K^T  (rows q, cols kv)
        f32x4 s[2][4];
        #pragma unroll
        for (int i = 0; i < 2; i++)
            #pragma unroll
            for (int j = 0; j < 4; j++) s[i][j] = (f32x4){0.f, 0.f, 0.f, 0.f};
        #pragma unroll
        for (int kt = 0; kt < 2; kt++)
            #pragma unroll
            for (int nt = 0; nt < 4; nt++) {
                short8 bk = *(const short8*)&Kl[(nt * 16 + c) * 72 + kt * 32 + kg];
                #pragma unroll
                for (int mt = 0; mt < 2; mt++)
                    s[mt][nt] = __builtin_amdgcn_mfma_f32_16x16x32_bf16(
                        aq[mt][kt], bk, s[mt][nt], 0, 0, 0);
            }

        // causal mask (wave-uniform branch)
        if (kv0 + 64 > qw) {
            #pragma unroll
            for (int mt = 0; mt < 2; mt++)
                #pragma unroll
                for (int nt = 0; nt < 4; nt++)
                    #pragma unroll
                    for (int j = 0; j < 4; j++) {
                        int kvc = kv0 + nt * 16 + c;
                        int qr  = qw + mt * 16 + r4 + j;
                        if (kvc > qr) s[mt][nt][j] = -1e30f;
                    }
        }

        // online softmax (row stats replicated across 16-lane groups)
        #pragma unroll
        for (int mt = 0; mt < 2; mt++) {
            float corr[4];
            #pragma unroll
            for (int j = 0; j < 4; j++) {
                float v = fmaxf(fmaxf(s[mt][0][j], s[mt][1][j]),
                                fmaxf(s[mt][2][j], s[mt][3][j]));
                #pragma unroll
                for (int off = 1; off < 16; off <<= 1)
                    v = fmaxf(v, __shfl_xor(v, off, 64));
                float mn = fmaxf(mrun[mt][j], v);
                corr[j] = __expf(mrun[mt][j] - mn);
                mrun[mt][j] = mn;
                float sum = 0.f;
                #pragma unroll
                for (int nt = 0; nt < 4; nt++) {
                    float p = __expf(s[mt][nt][j] - mn);
                    s[mt][nt][j] = p;
                    sum += p;
                }
                #pragma unroll
                for (int off = 1; off < 16; off <<= 1)
                    sum += __shfl_xor(sum, off, 64);
                lrun[mt][j] = lrun[mt][j] * corr[j] + sum;
            }
            #pragma unroll
            for (int nt = 0; nt < 4; nt++)
                #pragma unroll
                for (int j = 0; j < 4; j++) {
                    acc[mt][nt][j] *= corr[j];
                    Pl[wave * (32 * 72) + (mt * 16 + r4 + j) * 72 + nt * 16 + c]
                        = f2bf(s[mt][nt][j]);
                }
        }

        // O += P V   (A = P from LDS, B = V^T from Vt)
        #pragma unroll
        for (int kt = 0; kt < 2; kt++) {
            short8 pa[2];
            #pragma unroll
            for (int mt = 0; mt < 2; mt++)
                pa[mt] = *(const short8*)&Pl[wave * (32 * 72) + (mt * 16 + c) * 72 + kt * 32 + kg];
            #pragma unroll
            for (int nt = 0; nt < 4; nt++) {
                short8 bv = *(const short8*)&Vt[(nt * 16 + c) * 72 + kt * 32 + kg];
                #pragma unroll
                for (int mt = 0; mt < 2; mt++)
                    acc[mt][nt] = __builtin_amdgcn_mfma_f32_16x16x32_bf16(
                        pa[mt], bv, acc[mt][nt], 0, 0, 0);
            }
        }
    }

    // epilogue: normalize, write bf16 head-concat [B*S][1024]
    #pragma unroll
    for (int mt = 0; mt < 2; mt++)
        #pragma unroll
        for (int j = 0; j < 4; j++) {
            float inv = 1.0f / lrun[mt][j];
            int qr = qw + mt * 16 + r4 + j;
            int rowb = (b * SL + qr) * DM + h * DKH;
            #pragma unroll
            for (int nt = 0; nt < 4; nt++)
                O[rowb + nt * 16 + c] = f2bf(acc[mt][nt][j] * inv);
        }
}

// ---------------- launch -------------------------------------------------------
extern "C" void kernel_launch(void* const* d_in, const int* in_sizes, int n_in,
                              void* d_out, int out_size, void* d_ws, size_t ws_size,
                              hipStream_t stream)
{
    const float* x  = (const float*)d_in[0];
    const float* wq = (const float*)d_in[1];
    const float* wk = (const float*)d_in[2];
    const float* wv = (const float*)d_in[3];
    const float* wo = (const float*)d_in[4];
    char* ws = (char*)d_ws;
    unsigned short* xb  = (unsigned short*)(ws);                        // 8MB
    unsigned short* wqb = (unsigned short*)(ws + (8ll  << 20));         // 2MB (wq,wk,wv contiguous)
    unsigned short* wkb = (unsigned short*)(ws + (10ll << 20));
    unsigned short* wvb = (unsigned short*)(ws + (12ll << 20));
    unsigned short* wob = (unsigned short*)(ws + (14ll << 20));
    unsigned short* Qb  = (unsigned short*)(ws + (16ll << 20));         // 8MB each
    unsigned short* Kb  = (unsigned short*)(ws + (24ll << 20));
    unsigned short* Vb  = (unsigned short*)(ws + (32ll << 20));
    unsigned short* Abf = (unsigned short*)(ws + (40ll << 20));         // 8MB
    float* out = (float*)d_out;

    convert_kernel<<<dim3(8192), dim3(256), 0, stream>>>(
        x, wq, wk, wv, wo, xb, wqb, wkb, wvb, wob);

    // fused QKV projection: N = 3072 (wqb/wkb/wvb contiguous)
    gemm_bt<0><<<dim3(24, 32), dim3(256), 0, stream>>>(
        xb, wqb, Qb, Kb, Vb, (float*)nullptr);

    attn_kernel<<<dim3(SL / 128, NH, NB), dim3(256), 0, stream>>>(Qb, Kb, Vb, Abf);

    // output projection -> fp32 d_out
    gemm_bt<1><<<dim3(8, 32), dim3(256), 0, stream>>>(
        Abf, wob, nullptr, nullptr, nullptr, out);
}

// Round 2
// 138.486 us; speedup vs baseline: 1.4672x; 1.4672x over previous
//
#include <hip/hip_runtime.h>

typedef __attribute__((ext_vector_type(8))) short short8;
typedef __attribute__((ext_vector_type(4))) float f32x4;

#define DM 1024
#define SL 2048
#define NH 16
#define DKH 64
#define NB 2

__device__ __forceinline__ unsigned short f2bf(float f) {
    union { float f; unsigned int u; } a; a.f = f;
    unsigned int r = a.u + 0x7FFFu + ((a.u >> 16) & 1u);
    return (unsigned short)(r >> 16);
}

__device__ __forceinline__ void gl_lds16(const void* g, void* l) {
    __builtin_amdgcn_global_load_lds(
        (__attribute__((address_space(1))) void*)(g),
        (__attribute__((address_space(3))) void*)(l), 16, 0, 0);
}

// ---------------- fp32 -> bf16 conversion ---------------------------------------
// wq folded scale: 0.125 (1/sqrt(64)) * log2(e) so attention uses exp2 directly.
__global__ __launch_bounds__(256) void convert_kernel(
    const float* __restrict__ x,  const float* __restrict__ wq,
    const float* __restrict__ wk, const float* __restrict__ wv,
    const float* __restrict__ wo,
    unsigned short* __restrict__ xb,  unsigned short* __restrict__ wqb,
    unsigned short* __restrict__ wkb, unsigned short* __restrict__ wvb,
    unsigned short* __restrict__ wob)
{
    const int NX = NB * SL * DM;       // 4M
    const int NW = DM * DM;            // 1M
    int t4 = (blockIdx.x * 256 + threadIdx.x) * 4;
    const float* src; unsigned short* dst; int off; float scale = 1.0f;
    if (t4 < NX)              { src = x;  dst = xb;  off = t4; }
    else if (t4 < NX + NW)    { src = wq; dst = wqb; off = t4 - NX; scale = 0.125f * 1.44269504088896f; }
    else if (t4 < NX + 2*NW)  { src = wk; dst = wkb; off = t4 - NX - NW; }
    else if (t4 < NX + 3*NW)  { src = wv; dst = wvb; off = t4 - NX - 2*NW; }
    else                      { src = wo; dst = wob; off = t4 - NX - 3*NW; }
    float4 v = *(const float4*)(src + off);
    unsigned long long p =
        (unsigned long long)f2bf(v.x * scale)
      | ((unsigned long long)f2bf(v.y * scale) << 16)
      | ((unsigned long long)f2bf(v.z * scale) << 32)
      | ((unsigned long long)f2bf(v.w * scale) << 48);
    *(unsigned long long*)(dst + off) = p;
}

// ---------------- GEMM  C[m][n] = sum_k A[m][k] * Bw[n][k]  (both K-major) ------
template<int MODE>
__global__ __launch_bounds__(256) void gemm_bt(
    const unsigned short* __restrict__ A,
    const unsigned short* __restrict__ Bw,
    unsigned short* __restrict__ oq, unsigned short* __restrict__ ok,
    unsigned short* __restrict__ ov, float* __restrict__ of)
{
    __shared__ __align__(16) unsigned short As[128 * 32];
    __shared__ __align__(16) unsigned short Bs[128 * 32];
    const int tid  = threadIdx.x;
    const int lane = tid & 63;
    const int wave = tid >> 6;
    const int wm = (wave >> 1) * 64, wn = (wave & 1) * 64;
    const int bx = blockIdx.x, by = blockIdx.y;
    const int c  = lane & 15;
    const int kg = (lane >> 4) * 8;      // k sub-group (elems)

    f32x4 acc[4][4];
    #pragma unroll
    for (int i = 0; i < 4; i++)
        #pragma unroll
        for (int j = 0; j < 4; j++) acc[i][j] = (f32x4){0.f, 0.f, 0.f, 0.f};

    const char* Ab = (const char*)A  + by * 128 * (DM * 2);
    const char* Bb = (const char*)Bw + bx * 128 * (DM * 2);

    for (int k0 = 0; k0 < DM; k0 += 32) {
        #pragma unroll
        for (int i = 0; i < 2; i++) {
            int lin  = i * 4096 + tid * 16;   // bytes within 8KB tile
            int row  = lin >> 6;              // 64B per BK-row
            int colb = lin & 63;
            gl_lds16(Ab + row * (DM * 2) + k0 * 2 + colb, (char*)As + lin);
            gl_lds16(Bb + row * (DM * 2) + k0 * 2 + colb, (char*)Bs + lin);
        }
        __syncthreads();
        short8 a[4], bfr[4];
        #pragma unroll
        for (int mi = 0; mi < 4; mi++)
            a[mi] = *(const short8*)&As[(wm + mi * 16 + c) * 32 + kg];
        #pragma unroll
        for (int ni = 0; ni < 4; ni++)
            bfr[ni] = *(const short8*)&Bs[(wn + ni * 16 + c) * 32 + kg];
        #pragma unroll
        for (int mi = 0; mi < 4; mi++)
            #pragma unroll
            for (int ni = 0; ni < 4; ni++)
                acc[mi][ni] = __builtin_amdgcn_mfma_f32_16x16x32_bf16(
                    a[mi], bfr[ni], acc[mi][ni], 0, 0, 0);
        __syncthreads();
    }

    const int r4 = (lane >> 4) * 4;
    if (MODE == 0) {
        const int mat = (bx * 128) >> 10;                 // 0=q,1=k,2=v
        unsigned short* outb = (mat == 0) ? oq : (mat == 1) ? ok : ov;
        const int nb = bx * 128 - (mat << 10);
        #pragma unroll
        for (int mi = 0; mi < 4; mi++) {
            int m_g = by * 128 + wm + mi * 16 + r4;
            int b_  = m_g >> 11, s_ = m_g & 2047;
            #pragma unroll
            for (int ni = 0; ni < 4; ni++) {
                int n_l = nb + wn + ni * 16 + c;
                int h = n_l >> 6, dk = n_l & 63;
                #pragma unroll
                for (int j = 0; j < 4; j++)
                    outb[((b_ * NH + h) * SL + (s_ + j)) * DKH + dk] = f2bf(acc[mi][ni][j]);
            }
        }
    } else {
        #pragma unroll
        for (int mi = 0; mi < 4; mi++) {
            int m_g = by * 128 + wm + mi * 16 + r4;
            #pragma unroll
            for (int ni = 0; ni < 4; ni++) {
                int n_g = bx * 128 + wn + ni * 16 + c;
                #pragma unroll
                for (int j = 0; j < 4; j++)
                    of[(m_g + j) * DM + n_g] = acc[mi][ni][j];
            }
        }
    }
}

// ---------------- causal flash attention --------------------------------------
// Flat grid 1024 blocks: decode (qt, bh) with pairing remap so the 4 blocks
// co-resident on a CU (id, id+256, ...) get complementary causal depth
// (qt, 31-qt). QBLK=64: 4 waves x 16 q-rows; KV tiles of 64.
// Q is pre-scaled by 0.125*log2(e): softmax via exp2.
__global__ __launch_bounds__(256) void attn_kernel(
    const unsigned short* __restrict__ Q,   // [B*H][S][64] bf16
    const unsigned short* __restrict__ K,
    const unsigned short* __restrict__ V,
    unsigned short* __restrict__ O)         // [B*S][1024] bf16 head-concat
{
    __shared__ __align__(16) unsigned short Kl[64 * 72];       // [kv][dk], pad 8
    __shared__ __align__(16) unsigned short Vt[64 * 72];       // [dk][kv], pad 8
    __shared__ __align__(16) unsigned short Pl[4 * 16 * 72];   // per-wave [q][kv]
    const int tid = threadIdx.x, lane = tid & 63, wave = tid >> 6;
    const int id  = blockIdx.x;
    const int qtr = id & 31;
    const int bh  = (id >> 5) & 31;
    const int par = (id >> 8) & 1;
    const int qt  = par ? (31 - qtr) : qtr;
    const int b = bh >> 4, h = bh & 15;
    const int bhi = b * NH + h;
    const int qb = qt * 64;
    const int qw = qb + wave * 16;
    const unsigned short* Qg = Q + bhi * (SL * DKH);
    const unsigned short* Kg = K + bhi * (SL * DKH);
    const unsigned short* Vg = V + bhi * (SL * DKH);
    const int c  = lane & 15;
    const int kg = (lane >> 4) * 8;
    const int r4 = (lane >> 4) * 4;

    // Q fragments in registers (A-layout): 16 rows per wave
    short8 aq[2];
    #pragma unroll
    for (int kt = 0; kt < 2; kt++)
        aq[kt] = *(const short8*)&Qg[(qw + c) * DKH + kt * 32 + kg];

    f32x4 acc[4];
    #pragma unroll
    for (int j = 0; j < 4; j++) acc[j] = (f32x4){0.f, 0.f, 0.f, 0.f};
    float mrun[4], lsum[4];
    #pragma unroll
    for (int j = 0; j < 4; j++) { mrun[j] = -1e30f; lsum[j] = 0.f; }

    const int ntiles = qt + 1;   // kv < qb+64
    for (int t = 0; t < ntiles; ++t) {
        const int kv0 = t * 64;
        __syncthreads();   // protect prior-iter LDS reads from overwrite
        {   // stage K tile: coalesced 32B/thread
            int r = tid >> 2, cb = (tid & 3) << 4;
            const unsigned short* src = Kg + (kv0 + r) * DKH + cb;
            short8 v0 = *(const short8*)(src);
            short8 v1 = *(const short8*)(src + 8);
            *(short8*)&Kl[r * 72 + cb]     = v0;
            *(short8*)&Kl[r * 72 + cb + 8] = v1;
        }
        {   // stage V transposed: bf16x2 coalesced loads, b128 writes
            int d0 = (tid & 31) * 2, kc = (tid >> 5) * 8;
            short8 sa, sb;
            #pragma unroll
            for (int i = 0; i < 8; i++) {
                unsigned int pr = *(const unsigned int*)&Vg[(kv0 + kc + i) * DKH + d0];
                sa[i] = (short)(pr & 0xFFFFu);
                sb[i] = (short)(pr >> 16);
            }
            *(short8*)&Vt[d0 * 72 + kc]       = sa;
            *(short8*)&Vt[(d0 + 1) * 72 + kc] = sb;
        }
        __syncthreads();

        // S = Q K^T  (16 q-rows x 64 kv)
        f32x4 s[4];
        #pragma unroll
        for (int j = 0; j < 4; j++) s[j] = (f32x4){0.f, 0.f, 0.f, 0.f};
        #pragma unroll
        for (int kt = 0; kt < 2; kt++)
            #pragma unroll
            for (int nt = 0; nt < 4; nt++) {
                short8 bk = *(const short8*)&Kl[(nt * 16 + c) * 72 + kt * 32 + kg];
                s[nt] = __builtin_amdgcn_mfma_f32_16x16x32_bf16(
                    aq[kt], bk, s[nt], 0, 0, 0);
            }

        // causal mask: only the last tile straddles the diagonal
        if (t == ntiles - 1) {
            #pragma unroll
            for (int nt = 0; nt < 4; nt++)
                #pragma unroll
                for (int j = 0; j < 4; j++) {
                    int kvc = kv0 + nt * 16 + c;
                    int qr  = qw + r4 + j;
                    if (kvc > qr) s[nt][j] = -1e30f;
                }
        }

        // row max (4 shfl per row); defer-max rescale (THR=8 in log2 units)
        float vmax[4];
        #pragma unroll
        for (int j = 0; j < 4; j++) {
            float v = fmaxf(fmaxf(s[0][j], s[1][j]), fmaxf(s[2][j], s[3][j]));
            #pragma unroll
            for (int off = 1; off < 16; off <<= 1)
                v = fmaxf(v, __shfl_xor(v, off, 64));
            vmax[j] = v;
        }
        bool need = false;
        #pragma unroll
        for (int j = 0; j < 4; j++) need = need || (vmax[j] > mrun[j] + 8.f);
        if (__any(need)) {
            #pragma unroll
            for (int j = 0; j < 4; j++) {
                float mn = fmaxf(mrun[j], vmax[j]);
                float corr = exp2f(mrun[j] - mn);
                mrun[j] = mn;
                lsum[j] *= corr;
                #pragma unroll
                for (int nt = 0; nt < 4; nt++) acc[nt][j] *= corr;
            }
        }

        // P = exp2(S - m); per-lane partial sum (row reduce deferred to end)
        #pragma unroll
        for (int j = 0; j < 4; j++) {
            float ls = 0.f;
            #pragma unroll
            for (int nt = 0; nt < 4; nt++) {
                float p = exp2f(s[nt][j] - mrun[j]);
                ls += p;
                Pl[wave * (16 * 72) + (r4 + j) * 72 + nt * 16 + c] = f2bf(p);
            }
            lsum[j] += ls;
        }

        // O += P V   (A = P from LDS, B = V^T from Vt)
        #pragma unroll
        for (int kt = 0; kt < 2; kt++) {
            short8 pa = *(const short8*)&Pl[wave * (16 * 72) + c * 72 + kt * 32 + kg];
            #pragma unroll
            for (int nt = 0; nt < 4; nt++) {
                short8 bv = *(const short8*)&Vt[(nt * 16 + c) * 72 + kt * 32 + kg];
                acc[nt] = __builtin_amdgcn_mfma_f32_16x16x32_bf16(
                    pa, bv, acc[nt], 0, 0, 0);
            }
        }
    }

    // final row-sum reduce + normalize + write bf16 head-concat [B*S][1024]
    #pragma unroll
    for (int j = 0; j < 4; j++) {
        float tot = lsum[j];
        #pragma unroll
        for (int off = 1; off < 16; off <<= 1)
            tot += __shfl_xor(tot, off, 64);
        float inv = 1.0f / tot;
        int qr = qw + r4 + j;
        int rowb = (b * SL + qr) * DM + h * DKH;
        #pragma unroll
        for (int nt = 0; nt < 4; nt++)
            O[rowb + nt * 16 + c] = f2bf(acc[nt][j] * inv);
    }
}

// ---------------- launch -------------------------------------------------------
extern "C" void kernel_launch(void* const* d_in, const int* in_sizes, int n_in,
                              void* d_out, int out_size, void* d_ws, size_t ws_size,
                              hipStream_t stream)
{
    const float* x  = (const float*)d_in[0];
    const float* wq = (const float*)d_in[1];
    const float* wk = (const float*)d_in[2];
    const float* wv = (const float*)d_in[3];
    const float* wo = (const float*)d_in[4];
    char* ws = (char*)d_ws;
    unsigned short* xb  = (unsigned short*)(ws);                        // 8MB
    unsigned short* wqb = (unsigned short*)(ws + (8ll  << 20));         // 2MB (wq,wk,wv contiguous)
    unsigned short* wkb = (unsigned short*)(ws + (10ll << 20));
    unsigned short* wvb = (unsigned short*)(ws + (12ll << 20));
    unsigned short* wob = (unsigned short*)(ws + (14ll << 20));
    unsigned short* Qb  = (unsigned short*)(ws + (16ll << 20));         // 8MB each
    unsigned short* Kb  = (unsigned short*)(ws + (24ll << 20));
    unsigned short* Vb  = (unsigned short*)(ws + (32ll << 20));
    unsigned short* Abf = (unsigned short*)(ws + (40ll << 20));         // 8MB
    float* out = (float*)d_out;

    convert_kernel<<<dim3(8192), dim3(256), 0, stream>>>(
        x, wq, wk, wv, wo, xb, wqb, wkb, wvb, wob);

    // fused QKV projection: N = 3072 (wqb/wkb/wvb contiguous)
    gemm_bt<0><<<dim3(24, 32), dim3(256), 0, stream>>>(
        xb, wqb, Qb, Kb, Vb, (float*)nullptr);

    attn_kernel<<<dim3(1024), dim3(256), 0, stream>>>(Qb, Kb, Vb, Abf);

    // output projection -> fp32 d_out
    gemm_bt<1><<<dim3(8, 32), dim3(256), 0, stream>>>(
        Abf, wob, nullptr, nullptr, nullptr, out);
}

// Round 3
// 136.586 us; speedup vs baseline: 1.4876x; 1.0139x over previous
//
#include <hip/hip_runtime.h>

typedef __attribute__((ext_vector_type(8))) short short8;
typedef __attribute__((ext_vector_type(4))) float f32x4;

#define DM 1024
#define SL 2048
#define NH 16
#define DKH 64
#define NB 2

__device__ __forceinline__ unsigned short f2bf(float f) {
    union { float f; unsigned int u; } a; a.f = f;
    unsigned int r = a.u + 0x7FFFu + ((a.u >> 16) & 1u);
    return (unsigned short)(r >> 16);
}

__device__ __forceinline__ void gl_lds16(const void* g, void* l) {
    __builtin_amdgcn_global_load_lds(
        (__attribute__((address_space(1))) void*)(g),
        (__attribute__((address_space(3))) void*)(l), 16, 0, 0);
}

// ---------------- fp32 -> bf16 conversion ---------------------------------------
// wq folded scale: 0.125 (1/sqrt(64)) * log2(e) so attention uses exp2 directly.
__global__ __launch_bounds__(256) void convert_kernel(
    const float* __restrict__ x,  const float* __restrict__ wq,
    const float* __restrict__ wk, const float* __restrict__ wv,
    const float* __restrict__ wo,
    unsigned short* __restrict__ xb,  unsigned short* __restrict__ wqb,
    unsigned short* __restrict__ wkb, unsigned short* __restrict__ wvb,
    unsigned short* __restrict__ wob)
{
    const int NX = NB * SL * DM;       // 4M
    const int NW = DM * DM;            // 1M
    int t4 = (blockIdx.x * 256 + threadIdx.x) * 4;
    const float* src; unsigned short* dst; int off; float scale = 1.0f;
    if (t4 < NX)              { src = x;  dst = xb;  off = t4; }
    else if (t4 < NX + NW)    { src = wq; dst = wqb; off = t4 - NX; scale = 0.125f * 1.44269504088896f; }
    else if (t4 < NX + 2*NW)  { src = wk; dst = wkb; off = t4 - NX - NW; }
    else if (t4 < NX + 3*NW)  { src = wv; dst = wvb; off = t4 - NX - 2*NW; }
    else                      { src = wo; dst = wob; off = t4 - NX - 3*NW; }
    float4 v = *(const float4*)(src + off);
    unsigned long long p =
        (unsigned long long)f2bf(v.x * scale)
      | ((unsigned long long)f2bf(v.y * scale) << 16)
      | ((unsigned long long)f2bf(v.z * scale) << 32)
      | ((unsigned long long)f2bf(v.w * scale) << 48);
    *(unsigned long long*)(dst + off) = p;
}

// ---------------- GEMM  C[m][n] = sum_k A[m][k] * Bw[n][k]  (both K-major) ------
// BK=64, XOR-swizzled LDS (st-style: byte ^= (row&7)<<4), global_load_lds width16.
template<int MODE>
__global__ __launch_bounds__(256) void gemm_bt(
    const unsigned short* __restrict__ A,
    const unsigned short* __restrict__ Bw,
    unsigned short* __restrict__ oq, unsigned short* __restrict__ ok,
    unsigned short* __restrict__ ov, float* __restrict__ of)
{
    __shared__ __align__(16) unsigned short As[128 * 64];
    __shared__ __align__(16) unsigned short Bs[128 * 64];
    const int tid  = threadIdx.x;
    const int lane = tid & 63;
    const int wave = tid >> 6;
    const int wm = (wave >> 1) * 64, wn = (wave & 1) * 64;
    const int bx = blockIdx.x, by = blockIdx.y;
    const int c    = lane & 15;
    const int kg16 = (lane >> 4) * 16;     // byte offset of k-subgroup
    const int swz  = (c & 7) << 4;

    f32x4 acc[4][4];
    #pragma unroll
    for (int i = 0; i < 4; i++)
        #pragma unroll
        for (int j = 0; j < 4; j++) acc[i][j] = (f32x4){0.f, 0.f, 0.f, 0.f};

    const char* Ab = (const char*)A  + by * 128 * (DM * 2);
    const char* Bb = (const char*)Bw + bx * 128 * (DM * 2);

    for (int k0 = 0; k0 < DM; k0 += 64) {
        #pragma unroll
        for (int i = 0; i < 4; i++) {
            int o  = i * 4096 + tid * 16;     // byte offset in 16KB tile
            int r  = o >> 7;                  // 128B per BK-row
            int cb = o & 127;
            int src = r * (DM * 2) + k0 * 2 + (cb ^ ((r & 7) << 4));
            gl_lds16(Ab + src, (char*)As + o);
            gl_lds16(Bb + src, (char*)Bs + o);
        }
        __syncthreads();
        #pragma unroll
        for (int kk = 0; kk < 2; kk++) {
            short8 a[4], bfr[4];
            #pragma unroll
            for (int mi = 0; mi < 4; mi++)
                a[mi] = *(const short8*)((const char*)As
                        + (wm + mi * 16 + c) * 128 + ((kk * 64 + kg16) ^ swz));
            #pragma unroll
            for (int ni = 0; ni < 4; ni++)
                bfr[ni] = *(const short8*)((const char*)Bs
                        + (wn + ni * 16 + c) * 128 + ((kk * 64 + kg16) ^ swz));
            #pragma unroll
            for (int mi = 0; mi < 4; mi++)
                #pragma unroll
                for (int ni = 0; ni < 4; ni++)
                    acc[mi][ni] = __builtin_amdgcn_mfma_f32_16x16x32_bf16(
                        a[mi], bfr[ni], acc[mi][ni], 0, 0, 0);
        }
        __syncthreads();
    }

    const int r4 = (lane >> 4) * 4;
    if (MODE == 0) {
        const int mat = (bx * 128) >> 10;                 // 0=q,1=k,2=v
        unsigned short* outb = (mat == 0) ? oq : (mat == 1) ? ok : ov;
        const int nb = bx * 128 - (mat << 10);
        #pragma unroll
        for (int mi = 0; mi < 4; mi++) {
            int m_g = by * 128 + wm + mi * 16 + r4;
            int b_  = m_g >> 11, s_ = m_g & 2047;
            #pragma unroll
            for (int ni = 0; ni < 4; ni++) {
                int n_l = nb + wn + ni * 16 + c;
                int h = n_l >> 6, dk = n_l & 63;
                #pragma unroll
                for (int j = 0; j < 4; j++)
                    outb[((b_ * NH + h) * SL + (s_ + j)) * DKH + dk] = f2bf(acc[mi][ni][j]);
            }
        }
    } else {
        #pragma unroll
        for (int mi = 0; mi < 4; mi++) {
            int m_g = by * 128 + wm + mi * 16 + r4;
            #pragma unroll
            for (int ni = 0; ni < 4; ni++) {
                int n_g = bx * 128 + wn + ni * 16 + c;
                #pragma unroll
                for (int j = 0; j < 4; j++)
                    of[(m_g + j) * DM + n_g] = acc[mi][ni][j];
            }
        }
    }
}

// ---------------- causal flash attention --------------------------------------
// 512 blocks: (bh, p). Each block runs q-tile p then 31-p -> uniform 33 kv-tiles.
// QBLK=64 (4 waves x 16 q-rows), KV tiles of 64. K staged via global_load_lds
// with XOR swizzle, double-buffered; V reg-staged transposed, double-buffered;
// next tile's loads issued right after the barrier (fly under compute).
// Q pre-scaled by 0.125*log2(e): softmax via exp2.
__global__ __launch_bounds__(256) void attn_kernel(
    const unsigned short* __restrict__ Q,   // [B*H][S][64] bf16
    const unsigned short* __restrict__ K,
    const unsigned short* __restrict__ V,
    unsigned short* __restrict__ O)         // [B*S][1024] bf16 head-concat
{
    __shared__ __align__(16) unsigned short Kl[2][64 * 64];    // swizzled [kv][dk]
    __shared__ __align__(16) unsigned short Vt[2][64 * 72];    // [dk][kv], pad 8
    __shared__ __align__(16) unsigned short Pl[4][16 * 72];    // per-wave [q][kv]
    const int tid = threadIdx.x, lane = tid & 63, wave = tid >> 6;
    const int bh = blockIdx.x >> 4;          // 0..31
    const int p  = blockIdx.x & 15;          // 0..15
    const int b = bh >> 4, h = bh & 15;
    const int bhi = b * NH + h;
    const unsigned short* Qg = Q + bhi * (SL * DKH);
    const unsigned short* Kg = K + bhi * (SL * DKH);
    const unsigned short* Vg = V + bhi * (SL * DKH);
    const int c    = lane & 15;
    const int kg   = (lane >> 4) * 8;        // elems
    const int kg16 = (lane >> 4) * 16;       // bytes
    const int r4   = (lane >> 4) * 4;
    const int swz  = (c & 7) << 4;
    const int vd0 = (tid & 31) * 2, vkc = (tid >> 5) * 8;

    unsigned int vreg[8];

    for (int pass = 0; pass < 2; ++pass) {
        const int qt = pass ? (31 - p) : p;
        const int qw = qt * 64 + wave * 16;
        const int ntiles = qt + 1;

        // Q fragments (A-layout): 16 rows per wave
        short8 aq[2];
        #pragma unroll
        for (int kt = 0; kt < 2; kt++)
            aq[kt] = *(const short8*)&Qg[(qw + c) * DKH + kt * 32 + kg];

        f32x4 acc[4];
        #pragma unroll
        for (int j = 0; j < 4; j++) acc[j] = (f32x4){0.f, 0.f, 0.f, 0.f};
        float mrun[4], lsum[4];
        #pragma unroll
        for (int j = 0; j < 4; j++) { mrun[j] = -1e30f; lsum[j] = 0.f; }

        __syncthreads();   // protect LDS restage vs prior pass's reads
        // prologue: stage tile 0
        #pragma unroll
        for (int i = 0; i < 2; i++) {
            int o = i * 4096 + tid * 16;
            int r = o >> 7, cb = o & 127;
            gl_lds16((const char*)Kg + r * 128 + (cb ^ ((r & 7) << 4)),
                     (char*)&Kl[0][0] + o);
        }
        #pragma unroll
        for (int i = 0; i < 8; i++)
            vreg[i] = *(const unsigned int*)&Vg[(vkc + i) * DKH + vd0];

        for (int t = 0; t < ntiles; ++t) {
            const int buf = t & 1;
            {   // write prefetched V regs -> Vt[buf] (transposed)
                short8 sa, sb;
                #pragma unroll
                for (int i = 0; i < 8; i++) {
                    sa[i] = (short)(vreg[i] & 0xFFFFu);
                    sb[i] = (short)(vreg[i] >> 16);
                }
                *(short8*)&Vt[buf][vd0 * 72 + vkc]       = sa;
                *(short8*)&Vt[buf][(vd0 + 1) * 72 + vkc] = sb;
            }
            __syncthreads();   // barrier drain: Kl[buf] landed, Vt[buf] visible

            if (t + 1 < ntiles) {   // issue next tile's loads under this compute
                const int kv1 = (t + 1) * 64;
                #pragma unroll
                for (int i = 0; i < 2; i++) {
                    int o = i * 4096 + tid * 16;
                    int r = o >> 7, cb = o & 127;
                    gl_lds16((const char*)Kg + (kv1 + r) * 128 + (cb ^ ((r & 7) << 4)),
                             (char*)&Kl[buf ^ 1][0] + o);
                }
                #pragma unroll
                for (int i = 0; i < 8; i++)
                    vreg[i] = *(const unsigned int*)&Vg[(kv1 + vkc + i) * DKH + vd0];
            }

            // S = Q K^T  (16 q-rows x 64 kv)
            f32x4 s[4];
            #pragma unroll
            for (int j = 0; j < 4; j++) s[j] = (f32x4){0.f, 0.f, 0.f, 0.f};
            #pragma unroll
            for (int kt = 0; kt < 2; kt++)
                #pragma unroll
                for (int nt = 0; nt < 4; nt++) {
                    short8 bk = *(const short8*)((const char*)&Kl[buf][0]
                        + (nt * 16 + c) * 128 + ((kt * 64 + kg16) ^ swz));
                    s[nt] = __builtin_amdgcn_mfma_f32_16x16x32_bf16(
                        aq[kt], bk, s[nt], 0, 0, 0);
                }

            // causal mask: only the last tile straddles the diagonal
            if (t == ntiles - 1) {
                const int kv0 = t * 64;
                #pragma unroll
                for (int nt = 0; nt < 4; nt++)
                    #pragma unroll
                    for (int j = 0; j < 4; j++) {
                        int kvc = kv0 + nt * 16 + c;
                        int qr  = qw + r4 + j;
                        if (kvc > qr) s[nt][j] = -1e30f;
                    }
            }

            // row max (4 shfl per row); defer-max rescale (THR=8, log2 units)
            float vmax[4];
            #pragma unroll
            for (int j = 0; j < 4; j++) {
                float v = fmaxf(fmaxf(s[0][j], s[1][j]), fmaxf(s[2][j], s[3][j]));
                #pragma unroll
                for (int off = 1; off < 16; off <<= 1)
                    v = fmaxf(v, __shfl_xor(v, off, 64));
                vmax[j] = v;
            }
            bool need = false;
            #pragma unroll
            for (int j = 0; j < 4; j++) need = need || (vmax[j] > mrun[j] + 8.f);
            if (__any(need)) {
                #pragma unroll
                for (int j = 0; j < 4; j++) {
                    float mn = fmaxf(mrun[j], vmax[j]);
                    float corr = exp2f(mrun[j] - mn);
                    mrun[j] = mn;
                    lsum[j] *= corr;
                    #pragma unroll
                    for (int nt = 0; nt < 4; nt++) acc[nt][j] *= corr;
                }
            }

            // P = exp2(S - m); per-lane partial row sums
            #pragma unroll
            for (int j = 0; j < 4; j++) {
                float ls = 0.f;
                #pragma unroll
                for (int nt = 0; nt < 4; nt++) {
                    float pv = exp2f(s[nt][j] - mrun[j]);
                    ls += pv;
                    Pl[wave][(r4 + j) * 72 + nt * 16 + c] = f2bf(pv);
                }
                lsum[j] += ls;
            }

            // O += P V   (A = P from LDS, B = V^T from Vt)
            #pragma unroll
            for (int kt = 0; kt < 2; kt++) {
                short8 pa = *(const short8*)&Pl[wave][c * 72 + kt * 32 + kg];
                #pragma unroll
                for (int nt = 0; nt < 4; nt++) {
                    short8 bv = *(const short8*)&Vt[buf][(nt * 16 + c) * 72 + kt * 32 + kg];
                    acc[nt] = __builtin_amdgcn_mfma_f32_16x16x32_bf16(
                        pa, bv, acc[nt], 0, 0, 0);
                }
            }
        }

        // final row-sum reduce + normalize + write bf16 head-concat [B*S][1024]
        #pragma unroll
        for (int j = 0; j < 4; j++) {
            float tot = lsum[j];
            #pragma unroll
            for (int off = 1; off < 16; off <<= 1)
                tot += __shfl_xor(tot, off, 64);
            float inv = 1.0f / tot;
            int qr = qw + r4 + j;
            int rowb = (b * SL + qr) * DM + h * DKH;
            #pragma unroll
            for (int nt = 0; nt < 4; nt++)
                O[rowb + nt * 16 + c] = f2bf(acc[nt][j] * inv);
        }
    }
}

// ---------------- launch -------------------------------------------------------
extern "C" void kernel_launch(void* const* d_in, const int* in_sizes, int n_in,
                              void* d_out, int out_size, void* d_ws, size_t ws_size,
                              hipStream_t stream)
{
    const float* x  = (const float*)d_in[0];
    const float* wq = (const float*)d_in[1];
    const float* wk = (const float*)d_in[2];
    const float* wv = (const float*)d_in[3];
    const float* wo = (const float*)d_in[4];
    char* ws = (char*)d_ws;
    unsigned short* xb  = (unsigned short*)(ws);                        // 8MB
    unsigned short* wqb = (unsigned short*)(ws + (8ll  << 20));         // 2MB (wq,wk,wv contiguous)
    unsigned short* wkb = (unsigned short*)(ws + (10ll << 20));
    unsigned short* wvb = (unsigned short*)(ws + (12ll << 20));
    unsigned short* wob = (unsigned short*)(ws + (14ll << 20));
    unsigned short* Qb  = (unsigned short*)(ws + (16ll << 20));         // 8MB each
    unsigned short* Kb  = (unsigned short*)(ws + (24ll << 20));
    unsigned short* Vb  = (unsigned short*)(ws + (32ll << 20));
    unsigned short* Abf = (unsigned short*)(ws + (40ll << 20));         // 8MB
    float* out = (float*)d_out;

    convert_kernel<<<dim3(8192), dim3(256), 0, stream>>>(
        x, wq, wk, wv, wo, xb, wqb, wkb, wvb, wob);

    // fused QKV projection: N = 3072 (wqb/wkb/wvb contiguous)
    gemm_bt<0><<<dim3(24, 32), dim3(256), 0, stream>>>(
        xb, wqb, Qb, Kb, Vb, (float*)nullptr);

    attn_kernel<<<dim3(512), dim3(256), 0, stream>>>(Qb, Kb, Vb, Abf);

    // output projection -> fp32 d_out
    gemm_bt<1><<<dim3(8, 32), dim3(256), 0, stream>>>(
        Abf, wob, nullptr, nullptr, nullptr, out);
}

// Round 5
// 120.248 us; speedup vs baseline: 1.6898x; 1.1359x over previous
//
#include <hip/hip_runtime.h>

typedef __attribute__((ext_vector_type(8))) short short8;
typedef __attribute__((ext_vector_type(4))) float f32x4;
typedef __attribute__((ext_vector_type(16))) float f32x16;
typedef __attribute__((ext_vector_type(2))) unsigned int u32x2;

#define DM 1024
#define SL 2048
#define NH 16
#define DKH 64
#define NB 2

__device__ __forceinline__ unsigned short f2bf(float f) {
    union { float f; unsigned int u; } a; a.f = f;
    unsigned int r = a.u + 0x7FFFu + ((a.u >> 16) & 1u);
    return (unsigned short)(r >> 16);
}

__device__ __forceinline__ void gl_lds16(const void* g, void* l) {
    __builtin_amdgcn_global_load_lds(
        (__attribute__((address_space(1))) void*)(g),
        (__attribute__((address_space(3))) void*)(l), 16, 0, 0);
}

__device__ __forceinline__ unsigned int cvtpk_bf16(float lo, float hi) {
    unsigned int r;
    asm("v_cvt_pk_bf16_f32 %0, %1, %2" : "=v"(r) : "v"(lo), "v"(hi));
    return r;
}

// v_permlane32_swap_b32 semantics (m214-verified direction):
//   new_a[32:63] = old_b[0:31]; new_b[0:31] = old_a[32:63];
//   a[0:31], b[32:63] unchanged.
__device__ __forceinline__ void pl32swap(unsigned int &a, unsigned int &b) {
    u32x2 r = __builtin_amdgcn_permlane32_swap(a, b, false, false);
    a = r[0]; b = r[1];
}
__device__ __forceinline__ void pl32swapf(float &a, float &b) {
    unsigned int ua = __float_as_uint(a), ub = __float_as_uint(b);
    pl32swap(ua, ub);
    a = __uint_as_float(ua); b = __uint_as_float(ub);
}

// ---------------- fp32 -> bf16 conversion ---------------------------------------
// wq folded scale: 0.125 (1/sqrt(64)) * log2(e) so attention uses exp2 directly.
__global__ __launch_bounds__(256) void convert_kernel(
    const float* __restrict__ x,  const float* __restrict__ wq,
    const float* __restrict__ wk, const float* __restrict__ wv,
    const float* __restrict__ wo,
    unsigned short* __restrict__ xb,  unsigned short* __restrict__ wqb,
    unsigned short* __restrict__ wkb, unsigned short* __restrict__ wvb,
    unsigned short* __restrict__ wob)
{
    const int NX = NB * SL * DM;       // 4M
    const int NW = DM * DM;            // 1M
    int t4 = (blockIdx.x * 256 + threadIdx.x) * 4;
    const float* src; unsigned short* dst; int off; float scale = 1.0f;
    if (t4 < NX)              { src = x;  dst = xb;  off = t4; }
    else if (t4 < NX + NW)    { src = wq; dst = wqb; off = t4 - NX; scale = 0.125f * 1.44269504088896f; }
    else if (t4 < NX + 2*NW)  { src = wk; dst = wkb; off = t4 - NX - NW; }
    else if (t4 < NX + 3*NW)  { src = wv; dst = wvb; off = t4 - NX - 2*NW; }
    else                      { src = wo; dst = wob; off = t4 - NX - 3*NW; }
    float4 v = *(const float4*)(src + off);
    unsigned long long p =
        (unsigned long long)f2bf(v.x * scale)
      | ((unsigned long long)f2bf(v.y * scale) << 16)
      | ((unsigned long long)f2bf(v.z * scale) << 32)
      | ((unsigned long long)f2bf(v.w * scale) << 48);
    *(unsigned long long*)(dst + off) = p;
}

// ---------------- GEMM  C[m][n] = sum_k A[m][k] * Bw[n][k]  (both K-major) ------
// BK=64, XOR-swizzled LDS, global_load_lds width16.
template<int MODE>
__global__ __launch_bounds__(256) void gemm_bt(
    const unsigned short* __restrict__ A,
    const unsigned short* __restrict__ Bw,
    unsigned short* __restrict__ oq, unsigned short* __restrict__ ok,
    unsigned short* __restrict__ ov, float* __restrict__ of)
{
    __shared__ __align__(16) unsigned short As[128 * 64];
    __shared__ __align__(16) unsigned short Bs[128 * 64];
    const int tid  = threadIdx.x;
    const int lane = tid & 63;
    const int wave = tid >> 6;
    const int wm = (wave >> 1) * 64, wn = (wave & 1) * 64;
    const int bx = blockIdx.x, by = blockIdx.y;
    const int c    = lane & 15;
    const int kg16 = (lane >> 4) * 16;     // byte offset of k-subgroup
    const int swz  = (c & 7) << 4;

    f32x4 acc[4][4];
    #pragma unroll
    for (int i = 0; i < 4; i++)
        #pragma unroll
        for (int j = 0; j < 4; j++) acc[i][j] = (f32x4){0.f, 0.f, 0.f, 0.f};

    const char* Ab = (const char*)A  + by * 128 * (DM * 2);
    const char* Bb = (const char*)Bw + bx * 128 * (DM * 2);

    for (int k0 = 0; k0 < DM; k0 += 64) {
        #pragma unroll
        for (int i = 0; i < 4; i++) {
            int o  = i * 4096 + tid * 16;     // byte offset in 16KB tile
            int r  = o >> 7;                  // 128B per BK-row
            int cb = o & 127;
            int src = r * (DM * 2) + k0 * 2 + (cb ^ ((r & 7) << 4));
            gl_lds16(Ab + src, (char*)As + o);
            gl_lds16(Bb + src, (char*)Bs + o);
        }
        __syncthreads();
        #pragma unroll
        for (int kk = 0; kk < 2; kk++) {
            short8 a[4], bfr[4];
            #pragma unroll
            for (int mi = 0; mi < 4; mi++)
                a[mi] = *(const short8*)((const char*)As
                        + (wm + mi * 16 + c) * 128 + ((kk * 64 + kg16) ^ swz));
            #pragma unroll
            for (int ni = 0; ni < 4; ni++)
                bfr[ni] = *(const short8*)((const char*)Bs
                        + (wn + ni * 16 + c) * 128 + ((kk * 64 + kg16) ^ swz));
            #pragma unroll
            for (int mi = 0; mi < 4; mi++)
                #pragma unroll
                for (int ni = 0; ni < 4; ni++)
                    acc[mi][ni] = __builtin_amdgcn_mfma_f32_16x16x32_bf16(
                        a[mi], bfr[ni], acc[mi][ni], 0, 0, 0);
        }
        __syncthreads();
    }

    const int r4 = (lane >> 4) * 4;
    if (MODE == 0) {
        const int mat = (bx * 128) >> 10;                 // 0=q,1=k,2=v
        unsigned short* outb = (mat == 0) ? oq : (mat == 1) ? ok : ov;
        const int nb = bx * 128 - (mat << 10);
        #pragma unroll
        for (int mi = 0; mi < 4; mi++) {
            int m_g = by * 128 + wm + mi * 16 + r4;
            int b_  = m_g >> 11, s_ = m_g & 2047;
            #pragma unroll
            for (int ni = 0; ni < 4; ni++) {
                int n_l = nb + wn + ni * 16 + c;
                int h = n_l >> 6, dk = n_l & 63;
                #pragma unroll
                for (int j = 0; j < 4; j++)
                    outb[((b_ * NH + h) * SL + (s_ + j)) * DKH + dk] = f2bf(acc[mi][ni][j]);
            }
        }
    } else {
        #pragma unroll
        for (int mi = 0; mi < 4; mi++) {
            int m_g = by * 128 + wm + mi * 16 + r4;
            #pragma unroll
            for (int ni = 0; ni < 4; ni++) {
                int n_g = bx * 128 + wn + ni * 16 + c;
                #pragma unroll
                for (int j = 0; j < 4; j++)
                    of[(m_g + j) * DM + n_g] = acc[mi][ni][j];
            }
        }
    }
}

// ---------------- causal flash attention: swapped-QK^T 32x32 structure ---------
// grid 512: id = qt_raw*32 + bh; qt = qt_raw<8 ? qt_raw : 23-qt_raw (co-resident
// pairs sum to 17 tiles). QBLK=128 (4 waves x 32 q-rows), KV tile = 128 (2x64).
// S^T = mfma(K, Q): lane owns q-row lane&31; P built in-register via
// cvt_pk_bf16 + permlane32_swap; O^T = mfma(V^T, P): rescale lane-uniform.
// K in LDS via global_load_lds w/ source XOR (k8 ^= kv&7); V^T subtiled
// [kv8][d][8] (phase-conflict-free b128 reads).
__global__ __launch_bounds__(256) void attn_kernel(
    const unsigned short* __restrict__ Q,   // [B*H][S][64] bf16 (pre-scaled)
    const unsigned short* __restrict__ K,
    const unsigned short* __restrict__ V,
    unsigned short* __restrict__ O)         // [B*S][1024] bf16 head-concat
{
    __shared__ __align__(16) unsigned short Kl[2][128 * 64];   // 16KB each
    __shared__ __align__(16) unsigned short Vt[2][16 * 64 * 8];// 16KB each
    const int tid = threadIdx.x, lane = tid & 63, wave = tid >> 6;
    const int ln31 = lane & 31, hi = lane >> 5;
    const int qt_raw = blockIdx.x >> 5;
    const int bh     = blockIdx.x & 31;
    const int qt = qt_raw < 8 ? qt_raw : 23 - qt_raw;
    const int b = bh >> 4, h = bh & 15;
    const int bhi = b * NH + h;
    const unsigned short* Qg = Q + bhi * (SL * DKH);
    const unsigned short* Kg = K + bhi * (SL * DKH);
    const unsigned short* Vg = V + bhi * (SL * DKH);
    const int qw = qt * 128 + wave * 32;
    const int ntiles = qt + 1;
    const int vd0 = (tid & 31) * 2, c0 = tid >> 5;   // V stage mapping

    // Q B-fragments: lane holds Q[qw+ln31][ks*16 + hi*8 .. +7]
    short8 qf[4];
    #pragma unroll
    for (int ks = 0; ks < 4; ks++)
        qf[ks] = *(const short8*)&Qg[(qw + ln31) * DKH + ks * 16 + hi * 8];

    f32x16 OT0, OT1;
    #pragma unroll
    for (int r = 0; r < 16; r++) { OT0[r] = 0.f; OT1[r] = 0.f; }
    float mrun = -1e30f, ls = 0.f;

    unsigned int vreg[16];

    // prologue: stage tile 0
    #pragma unroll
    for (int i = 0; i < 4; i++) {
        int s = i * 256 + tid;
        int kv = s >> 3;
        int k8 = (s & 7) ^ (kv & 7);
        gl_lds16((const char*)Kg + kv * 128 + k8 * 16, (char*)&Kl[0][0] + s * 16);
    }
    #pragma unroll
    for (int c2 = 0; c2 < 2; c2++)
        #pragma unroll
        for (int i = 0; i < 8; i++)
            vreg[c2 * 8 + i] = *(const unsigned int*)&Vg[((c0 + c2 * 8) * 8 + i) * DKH + vd0];

    for (int t = 0; t < ntiles; ++t) {
        const int buf = t & 1;
        const int kv0 = t * 128;
        // write staged V regs -> Vt[buf], subtile layout [kv8][d][8]
        #pragma unroll
        for (int c2 = 0; c2 < 2; c2++) {
            int chunk = c0 + c2 * 8;
            short8 sa, sb;
            #pragma unroll
            for (int i = 0; i < 8; i++) {
                unsigned int pr = vreg[c2 * 8 + i];
                sa[i] = (short)(pr & 0xFFFFu);
                sb[i] = (short)(pr >> 16);
            }
            *(short8*)&Vt[buf][(chunk * 64 + vd0) * 8]     = sa;
            *(short8*)&Vt[buf][(chunk * 64 + vd0 + 1) * 8] = sb;
        }
        __syncthreads();   // drains gl_lds for Kl[buf]; Vt[buf] visible

        if (t + 1 < ntiles) {   // prefetch next tile under this compute
            const int kv1 = (t + 1) * 128;
            #pragma unroll
            for (int i = 0; i < 4; i++) {
                int s = i * 256 + tid;
                int kv = s >> 3;
                int k8 = (s & 7) ^ (kv & 7);
                gl_lds16((const char*)Kg + (size_t)(kv1 + kv) * 128 + k8 * 16,
                         (char*)&Kl[buf ^ 1][0] + s * 16);
            }
            #pragma unroll
            for (int c2 = 0; c2 < 2; c2++)
                #pragma unroll
                for (int i = 0; i < 8; i++)
                    vreg[c2 * 8 + i] = *(const unsigned int*)&Vg[(size_t)(kv1 + (c0 + c2 * 8) * 8 + i) * DKH + vd0];
        }

        const char* kb = (const char*)&Kl[buf][0];
        const unsigned short* vb = &Vt[buf][0];
        #pragma unroll
        for (int hh = 0; hh < 2; hh++) {
            const int kvh = kv0 + hh * 64;
            if (kvh > qw + 31) break;   // fully masked half (wave-uniform)

            // S^T = K . Q^T  : two 32-kv subtiles
            f32x16 S0, S1;
            #pragma unroll
            for (int r = 0; r < 16; r++) { S0[r] = 0.f; S1[r] = 0.f; }
            #pragma unroll
            for (int ks = 0; ks < 4; ks++) {
                int ko = (ks * 32 + hi * 16) ^ ((ln31 & 7) << 4);
                short8 ka0 = *(const short8*)(kb + (hh * 64 + ln31) * 128 + ko);
                short8 ka1 = *(const short8*)(kb + (hh * 64 + 32 + ln31) * 128 + ko);
                S0 = __builtin_amdgcn_mfma_f32_32x32x16_bf16(ka0, qf[ks], S0, 0, 0, 0);
                S1 = __builtin_amdgcn_mfma_f32_32x32x16_bf16(ka1, qf[ks], S1, 0, 0, 0);
            }

            // causal mask (only straddling halves)
            if (kvh + 63 > qw) {
                const int qrel0 = qw + ln31 - kvh - 4 * hi;
                const int qrel1 = qrel0 - 32;
                #pragma unroll
                for (int r = 0; r < 16; r++) {
                    const int ro = (r & 3) + 8 * (r >> 2);
                    if (ro > qrel0) S0[r] = -1e30f;
                    if (ro > qrel1) S1[r] = -1e30f;
                }
            }

            // row max: in-reg tree + 1 permlane swap
            float mx = fmaxf(S0[0], S1[0]);
            #pragma unroll
            for (int r = 1; r < 16; r++) mx = fmaxf(mx, fmaxf(S0[r], S1[r]));
            float ma = mx, mb = mx;
            pl32swapf(ma, mb);
            float rm = fmaxf(ma, mb);

            // defer-max rescale (THR=8 in log2 units)
            if (__any(rm > mrun + 8.f)) {
                float nm = fmaxf(mrun, rm);
                float corr = exp2f(mrun - nm);
                mrun = nm; ls *= corr;
                #pragma unroll
                for (int r = 0; r < 16; r++) { OT0[r] *= corr; OT1[r] *= corr; }
            }

            // P = exp2(S - m) in place; per-lane half-row sum
            float psum = 0.f;
            #pragma unroll
            for (int r = 0; r < 16; r++) {
                S0[r] = exp2f(S0[r] - mrun); psum += S0[r];
                S1[r] = exp2f(S1[r] - mrun); psum += S1[r];
            }
            ls += psum;

            // build P B-fragments in-register (T12, m214-verified ordering):
            // pl32swap(pack(S[2i],S[2i+1]), pack(S[2i+4],S[2i+5])) -> (word_lo, word_hi)
            short8 pf[4];
            {
                unsigned int wa, wb, wc, wd;
                wa = cvtpk_bf16(S0[0], S0[1]);   wb = cvtpk_bf16(S0[4], S0[5]);
                pl32swap(wa, wb);                // wa=word0, wb=word2
                wc = cvtpk_bf16(S0[2], S0[3]);   wd = cvtpk_bf16(S0[6], S0[7]);
                pl32swap(wc, wd);                // wc=word1, wd=word3
                union { unsigned int u[4]; short8 s; } w0 = {{wa, wc, wb, wd}};
                pf[0] = w0.s;

                wa = cvtpk_bf16(S0[8], S0[9]);   wb = cvtpk_bf16(S0[12], S0[13]);
                pl32swap(wa, wb);
                wc = cvtpk_bf16(S0[10], S0[11]); wd = cvtpk_bf16(S0[14], S0[15]);
                pl32swap(wc, wd);
                union { unsigned int u[4]; short8 s; } w1 = {{wa, wc, wb, wd}};
                pf[1] = w1.s;

                wa = cvtpk_bf16(S1[0], S1[1]);   wb = cvtpk_bf16(S1[4], S1[5]);
                pl32swap(wa, wb);
                wc = cvtpk_bf16(S1[2], S1[3]);   wd = cvtpk_bf16(S1[6], S1[7]);
                pl32swap(wc, wd);
                union { unsigned int u[4]; short8 s; } w2 = {{wa, wc, wb, wd}};
                pf[2] = w2.s;

                wa = cvtpk_bf16(S1[8], S1[9]);   wb = cvtpk_bf16(S1[12], S1[13]);
                pl32swap(wa, wb);
                wc = cvtpk_bf16(S1[10], S1[11]); wd = cvtpk_bf16(S1[14], S1[15]);
                pl32swap(wc, wd);
                union { unsigned int u[4]; short8 s; } w3 = {{wa, wc, wb, wd}};
                pf[3] = w3.s;
            }

            // O^T += V^T . P  (A = V^T from subtiled Vt, B = P in-reg)
            #pragma unroll
            for (int ks2 = 0; ks2 < 4; ks2++) {
                int slot = (hh * 8 + ks2 * 2 + hi) * 64;
                short8 va0 = *(const short8*)&vb[(slot + ln31) * 8];
                short8 va1 = *(const short8*)&vb[(slot + 32 + ln31) * 8];
                OT0 = __builtin_amdgcn_mfma_f32_32x32x16_bf16(va0, pf[ks2], OT0, 0, 0, 0);
                OT1 = __builtin_amdgcn_mfma_f32_32x32x16_bf16(va1, pf[ks2], OT1, 0, 0, 0);
            }
        }
    }

    // epilogue: combine half-row sums, normalize, write bf16 [B*S][1024]
    float la = ls, lb = ls;
    pl32swapf(la, lb);
    float inv = 1.0f / (la + lb);
    const int qrow = qw + ln31;
    const size_t base = (size_t)(b * SL + qrow) * DM + h * DKH;
    #pragma unroll
    for (int r = 0; r < 16; r++) {
        const int d0 = (r & 3) + 8 * (r >> 2) + 4 * hi;
        O[base + d0]      = f2bf(OT0[r] * inv);
        O[base + 32 + d0] = f2bf(OT1[r] * inv);
    }
}

// ---------------- launch -------------------------------------------------------
extern "C" void kernel_launch(void* const* d_in, const int* in_sizes, int n_in,
                              void* d_out, int out_size, void* d_ws, size_t ws_size,
                              hipStream_t stream)
{
    const float* x  = (const float*)d_in[0];
    const float* wq = (const float*)d_in[1];
    const float* wk = (const float*)d_in[2];
    const float* wv = (const float*)d_in[3];
    const float* wo = (const float*)d_in[4];
    char* ws = (char*)d_ws;
    unsigned short* xb  = (unsigned short*)(ws);                        // 8MB
    unsigned short* wqb = (unsigned short*)(ws + (8ll  << 20));         // 2MB (wq,wk,wv contiguous)
    unsigned short* wkb = (unsigned short*)(ws + (10ll << 20));
    unsigned short* wvb = (unsigned short*)(ws + (12ll << 20));
    unsigned short* wob = (unsigned short*)(ws + (14ll << 20));
    unsigned short* Qb  = (unsigned short*)(ws + (16ll << 20));         // 8MB each
    unsigned short* Kb  = (unsigned short*)(ws + (24ll << 20));
    unsigned short* Vb  = (unsigned short*)(ws + (32ll << 20));
    unsigned short* Abf = (unsigned short*)(ws + (40ll << 20));         // 8MB
    float* out = (float*)d_out;

    convert_kernel<<<dim3(8192), dim3(256), 0, stream>>>(
        x, wq, wk, wv, wo, xb, wqb, wkb, wvb, wob);

    // fused QKV projection: N = 3072 (wqb/wkb/wvb contiguous)
    gemm_bt<0><<<dim3(24, 32), dim3(256), 0, stream>>>(
        xb, wqb, Qb, Kb, Vb, (float*)nullptr);

    attn_kernel<<<dim3(512), dim3(256), 0, stream>>>(Qb, Kb, Vb, Abf);

    // output projection -> fp32 d_out
    gemm_bt<1><<<dim3(8, 32), dim3(256), 0, stream>>>(
        Abf, wob, nullptr, nullptr, nullptr, out);
}